// Round 1
// baseline (403.387 us; speedup 1.0000x reference)
//
#include <hip/hip_runtime.h>
#include <hip/hip_bf16.h>

typedef __attribute__((ext_vector_type(8))) short short8;
typedef __attribute__((ext_vector_type(4))) float float4v;
typedef __attribute__((ext_vector_type(4))) unsigned int uint4v;

#define DDIM 1024
#define M_TILE 64
#define ETH_STRIDE 1032   // 1024 + 8 bf16 pad (16B) -> 2-way LDS aliasing (free)

__device__ __forceinline__ unsigned short f2bf(float f) {
  unsigned u = __builtin_bit_cast(unsigned, f);
  unsigned r = (u + 0x7fffu + ((u >> 16) & 1u)) >> 16;   // RNE
  return (unsigned short)r;
}
__device__ __forceinline__ unsigned pk2(float lo, float hi) {
  return (unsigned)f2bf(lo) | ((unsigned)f2bf(hi) << 16);
}

// ---- prepass: W fp32 -> bf16 in workspace (2 MB; L2-resident thereafter) ----
__global__ __launch_bounds__(256) void convert_w(const float* __restrict__ W,
                                                 unsigned short* __restrict__ Wb) {
  size_t i = ((size_t)blockIdx.x * 256 + threadIdx.x) * 8;
  float4v a = *(const float4v*)(W + i);
  float4v b = *(const float4v*)(W + i + 4);
  uint4v pk;
  pk.x = pk2(a.x, a.y); pk.y = pk2(a.z, a.w);
  pk.z = pk2(b.x, b.y); pk.w = pk2(b.z, b.w);
  *(uint4v*)(Wb + i) = pk;
}

// ---- fused bilinear: out[n] = elg[n] . (eth[n] @ W^T) ----
// block = 256 thr (4 waves), 64 eth rows LDS-resident bf16, d swept in 4x256 tiles,
// K-loop BK=32 with register-double-buffered W staging. Wave tile 64x64 (4x4 MFMA 16x16x32).
__global__ __launch_bounds__(256) void bilinear_kernel(const float* __restrict__ elg,
                                                       const float* __restrict__ eth,
                                                       const unsigned short* __restrict__ Wb,
                                                       float* __restrict__ out) {
  __shared__ unsigned short ethL[M_TILE * ETH_STRIDE]; // 132096 B
  __shared__ unsigned short Wbuf[256 * 32];            // 16384 B, XOR-swizzled 16B units
  __shared__ float wsum[4][64];                        // 1024 B

  const int tid  = threadIdx.x;
  const int lane = tid & 63;
  const int w    = tid >> 6;      // wave 0..3 -> d-column slice
  const int quad = lane >> 4;
  const int l15  = lane & 15;
  const int m0   = blockIdx.x * M_TILE;

  // prefetch W chunk 0 into registers (in flight during eth staging)
  uint4v wreg[4];
  {
    const int rbase = tid >> 2, up = tid & 3;
#pragma unroll
    for (int i = 0; i < 4; ++i) {
      int r = rbase + 64 * i;                 // chunk-local d row
      int u = up ^ ((r >> 1) & 3);            // logical 16B unit for phys slot up
      wreg[i] = *(const uint4v*)(Wb + (size_t)r * DDIM + u * 8);
    }
  }

  // stage eth rows [m0, m0+64) -> LDS bf16 (each element read once from HBM)
#pragma unroll
  for (int it = 0; it < 32; ++it) {
    int g = tid + 256 * it;
    int row = g >> 7, cg = g & 127;
    const float* src = eth + (size_t)(m0 + row) * DDIM + cg * 8;
    float4v a = *(const float4v*)(src);
    float4v b = *(const float4v*)(src + 4);
    uint4v pk;
    pk.x = pk2(a.x, a.y); pk.y = pk2(a.z, a.w);
    pk.z = pk2(b.x, b.y); pk.w = pk2(b.z, b.w);
    *(uint4v*)&ethL[row * ETH_STRIDE + cg * 8] = pk;
  }

  float p[16];
#pragma unroll
  for (int j = 0; j < 16; ++j) p[j] = 0.f;

  for (int dIter = 0; dIter < 4; ++dIter) {
    const int d0 = dIter * 256;
    float4v acc[4][4];
#pragma unroll
    for (int ct = 0; ct < 4; ++ct)
#pragma unroll
      for (int rt = 0; rt < 4; ++rt)
        acc[ct][rt] = (float4v){0.f, 0.f, 0.f, 0.f};

    for (int ek = 0; ek < 32; ++ek) {
      __syncthreads();                         // prev compute done -> Wbuf reusable
#pragma unroll
      for (int i = 0; i < 4; ++i)              // regs -> LDS (vmcnt wait auto-inserted)
        *(uint4v*)&Wbuf[tid * 8 + i * 2048] = wreg[i];
      __syncthreads();                         // staged chunk visible

      // prefetch next chunk into regs; latency hidden behind this chunk's MFMAs
      int cN = dIter * 32 + ek + 1;
      if (cN < 128) {
        int d0n = (cN >> 5) * 256, e0n = (cN & 31) * 32;
        const int rbase = tid >> 2, up = tid & 3;
#pragma unroll
        for (int i = 0; i < 4; ++i) {
          int r = rbase + 64 * i;
          int u = up ^ ((r >> 1) & 3);
          wreg[i] = *(const uint4v*)(Wb + (size_t)(d0n + r) * DDIM + e0n + u * 8);
        }
      }

      short8 aF[4], bF[4];
#pragma unroll
      for (int rt = 0; rt < 4; ++rt)           // A[m=l15][k=quad*8+j], 2-way bank (free)
        aF[rt] = *(const short8*)&ethL[(rt * 16 + l15) * ETH_STRIDE + ek * 32 + quad * 8];
#pragma unroll
      for (int ct = 0; ct < 4; ++ct) {         // B[k][n=l15] = Wrow[n][k], swizzled (free)
        int r = w * 64 + ct * 16 + l15;
        int pu = quad ^ ((r >> 1) & 3);
        bF[ct] = *(const short8*)&Wbuf[r * 32 + pu * 8];
      }
#pragma unroll
      for (int ct = 0; ct < 4; ++ct)
#pragma unroll
        for (int rt = 0; rt < 4; ++rt)
          acc[ct][rt] = __builtin_amdgcn_mfma_f32_16x16x32_bf16(aF[rt], bF[ct], acc[ct][rt], 0, 0, 0);
    }

    // fused epilogue: p[m] += elg[m][d] * u[m][d] for this d-tile (elg stays fp32)
#pragma unroll
    for (int ct = 0; ct < 4; ++ct) {
      int col = d0 + w * 64 + ct * 16 + l15;
#pragma unroll
      for (int rt = 0; rt < 4; ++rt) {
        const float* ep = elg + (size_t)(m0 + rt * 16 + quad * 4) * DDIM + col;
#pragma unroll
        for (int i = 0; i < 4; ++i)
          p[rt * 4 + i] += acc[ct][rt][i] * ep[(size_t)i * DDIM];
      }
    }
  }

  // reduce partials over the 16 lanes that share each row set
#pragma unroll
  for (int off = 1; off < 16; off <<= 1)
#pragma unroll
    for (int j = 0; j < 16; ++j)
      p[j] += __shfl_xor(p[j], off);

  if (l15 == 0) {
#pragma unroll
    for (int rt = 0; rt < 4; ++rt)
#pragma unroll
      for (int i = 0; i < 4; ++i)
        wsum[w][rt * 16 + quad * 4 + i] = p[rt * 4 + i];
  }
  __syncthreads();
  if (tid < 64)
    out[m0 + tid] = wsum[0][tid] + wsum[1][tid] + wsum[2][tid] + wsum[3][tid];
}

extern "C" void kernel_launch(void* const* d_in, const int* in_sizes, int n_in,
                              void* d_out, int out_size, void* d_ws, size_t ws_size,
                              hipStream_t stream) {
  (void)in_sizes; (void)n_in; (void)out_size; (void)ws_size;
  const float* elg = (const float*)d_in[0];
  const float* eth = (const float*)d_in[1];
  const float* W   = (const float*)d_in[2];
  float* out = (float*)d_out;
  unsigned short* Wb = (unsigned short*)d_ws;   // needs 2 MB of workspace

  convert_w<<<dim3(512), dim3(256), 0, stream>>>(W, Wb);
  bilinear_kernel<<<dim3(512), dim3(256), 0, stream>>>(elg, eth, Wb, out);
}

// Round 2
// 368.320 us; speedup vs baseline: 1.0952x; 1.0952x over previous
//
#include <hip/hip_runtime.h>
#include <hip/hip_bf16.h>

typedef __attribute__((ext_vector_type(8))) short short8;
typedef __attribute__((ext_vector_type(4))) float float4v;
typedef __attribute__((ext_vector_type(4))) unsigned int uint4v;

#define DDIM 1024
#define ETH_STRIDE 40   // 32 + 8 bf16 pad (16 B) -> row starts step 20 banks, 2-way (free)

__device__ __forceinline__ unsigned short f2bf(float f) {
  unsigned u = __builtin_bit_cast(unsigned, f);
  unsigned r = (u + 0x7fffu + ((u >> 16) & 1u)) >> 16;   // RNE
  return (unsigned short)r;
}
__device__ __forceinline__ unsigned pk2(float lo, float hi) {
  return (unsigned)f2bf(lo) | ((unsigned)f2bf(hi) << 16);
}

// ---- prepass: W fp32 -> bf16 in workspace (2 MB; L2-resident thereafter) ----
__global__ __launch_bounds__(256) void convert_w(const float* __restrict__ W,
                                                 unsigned short* __restrict__ Wb) {
  size_t i = ((size_t)blockIdx.x * 256 + threadIdx.x) * 8;
  float4v a = *(const float4v*)(W + i);
  float4v b = *(const float4v*)(W + i + 4);
  uint4v pk;
  pk.x = pk2(a.x, a.y); pk.y = pk2(a.z, a.w);
  pk.z = pk2(b.x, b.y); pk.w = pk2(b.z, b.w);
  *(uint4v*)(Wb + i) = pk;
}

// ---- fused bilinear, d-split: block = 64 rows x 256 d-cols, K=1024 ----
// grid 2048 = 512 m-groups x 4 d-tiles. LDS ~22.5 KB -> 3 blocks/CU (12 waves).
// W staged via global_load_lds (16B DMA, XOR-swizzled in global addr);
// eth staged via register-prefetched fp32 loads + RNE pack (overlaps MFMA).
__global__ __launch_bounds__(256, 3) void bilinear_kernel(const float* __restrict__ elg,
                                                          const float* __restrict__ eth,
                                                          const unsigned short* __restrict__ Wb,
                                                          float* __restrict__ out) {
  __shared__ unsigned short ethL[64 * ETH_STRIDE]; // 5120 B
  __shared__ unsigned short Wbuf[256 * 32];        // 16384 B, XOR-swizzled 16B units
  __shared__ float wsum[4][64];                    // 1024 B

  const int tid  = threadIdx.x;
  const int lane = tid & 63;
  const int w    = tid >> 6;       // wave 0..3 -> 64-wide d-column slice
  const int quad = lane >> 4;
  const int l15  = lane & 15;
  const int m0   = (blockIdx.x >> 2) * 64;
  const int d0   = (blockIdx.x & 3) * 256;

  // eth staging role: thread t -> row t>>2, 16B unit t&3 of the 32-wide chunk
  const int erow = tid >> 2, eunit = tid & 3;
  const float* esrc = eth + (size_t)(m0 + erow) * DDIM + eunit * 8;

  // W DMA role: within instr (w,j): lane -> row (w*4+j)*16 + (lane>>2), unit lane&3
  const int wr = lane >> 2, wu = lane & 3;

  // prefetch eth chunk 0
  float4v er0 = *(const float4v*)(esrc);
  float4v er1 = *(const float4v*)(esrc + 4);

  float4v acc[4][4];
#pragma unroll
  for (int ct = 0; ct < 4; ++ct)
#pragma unroll
    for (int rt = 0; rt < 4; ++rt)
      acc[ct][rt] = (float4v){0.f, 0.f, 0.f, 0.f};

  for (int ek = 0; ek < 32; ++ek) {
    const int e0 = ek * 32;
    __syncthreads();                       // buffers reusable (prev reads done)

    // eth chunk -> LDS (bf16)
    {
      uint4v pk;
      pk.x = pk2(er0.x, er0.y); pk.y = pk2(er0.z, er0.w);
      pk.z = pk2(er1.x, er1.y); pk.w = pk2(er1.z, er1.w);
      *(uint4v*)&ethL[erow * ETH_STRIDE + eunit * 8] = pk;
    }

    // W chunk -> LDS via DMA: 16 KB = 16 wave-instrs (4/wave), lane-order dest
#pragma unroll
    for (int j = 0; j < 4; ++j) {
      int r  = (w * 4 + j) * 16 + wr;           // chunk-local d row 0..255
      int ug = wu ^ ((r >> 1) & 3);             // swizzle in GLOBAL unit choice
      const unsigned short* gp = Wb + (size_t)(d0 + r) * DDIM + e0 + ug * 8;
      unsigned short* lp = &Wbuf[(w * 4 + j) * 512 + lane * 8];
      __builtin_amdgcn_global_load_lds(
          (const __attribute__((address_space(1))) unsigned int*)gp,
          (__attribute__((address_space(3))) unsigned int*)lp, 16, 0, 0);
    }
    __syncthreads();                       // staged chunk visible (DMA drained)

    short8 aF[4], bF[4];
#pragma unroll
    for (int rt = 0; rt < 4; ++rt)         // A[m=l15][k=quad*8+j]
      aF[rt] = *(const short8*)&ethL[(rt * 16 + l15) * ETH_STRIDE + quad * 8];
#pragma unroll
    for (int ct = 0; ct < 4; ++ct) {       // B[k][n=l15] = W row d, swizzled unit
      int dl = w * 64 + ct * 16 + l15;
      int pu = quad ^ ((dl >> 1) & 3);
      bF[ct] = *(const short8*)&Wbuf[dl * 32 + pu * 8];
    }

    // prefetch next eth chunk; overlaps the MFMA stretch, drains at next barrier
    if (ek < 31) {
      const float* s = esrc + (e0 + 32);
      er0 = *(const float4v*)(s);
      er1 = *(const float4v*)(s + 4);
    }

#pragma unroll
    for (int ct = 0; ct < 4; ++ct)
#pragma unroll
      for (int rt = 0; rt < 4; ++rt)
        acc[ct][rt] = __builtin_amdgcn_mfma_f32_16x16x32_bf16(aF[rt], bF[ct], acc[ct][rt], 0, 0, 0);
  }

  // fused epilogue: p[m] = sum_col elg[m][col] * u[m][col] over this d-tile
  float p[16];
#pragma unroll
  for (int j = 0; j < 16; ++j) p[j] = 0.f;
#pragma unroll
  for (int ct = 0; ct < 4; ++ct) {
    int col = d0 + w * 64 + ct * 16 + l15;
#pragma unroll
    for (int rt = 0; rt < 4; ++rt) {
      const float* ep = elg + (size_t)(m0 + rt * 16 + quad * 4) * DDIM + col;
#pragma unroll
      for (int i = 0; i < 4; ++i)
        p[rt * 4 + i] += acc[ct][rt][i] * ep[(size_t)i * DDIM];
    }
  }

  // reduce over the 16 lanes (cols) sharing each row
#pragma unroll
  for (int off = 1; off < 16; off <<= 1)
#pragma unroll
    for (int j = 0; j < 16; ++j)
      p[j] += __shfl_xor(p[j], off);

  if (l15 == 0) {
#pragma unroll
    for (int rt = 0; rt < 4; ++rt)
#pragma unroll
      for (int i = 0; i < 4; ++i)
        wsum[w][rt * 16 + quad * 4 + i] = p[rt * 4 + i];
  }
  __syncthreads();
  if (tid < 64) {
    float s = wsum[0][tid] + wsum[1][tid] + wsum[2][tid] + wsum[3][tid];
    atomicAdd(&out[m0 + tid], s);          // 4 d-tile blocks per output
  }
}

extern "C" void kernel_launch(void* const* d_in, const int* in_sizes, int n_in,
                              void* d_out, int out_size, void* d_ws, size_t ws_size,
                              hipStream_t stream) {
  (void)in_sizes; (void)n_in; (void)ws_size;
  const float* elg = (const float*)d_in[0];
  const float* eth = (const float*)d_in[1];
  const float* W   = (const float*)d_in[2];
  float* out = (float*)d_out;
  unsigned short* Wb = (unsigned short*)d_ws;   // needs 2 MB of workspace

  hipMemsetAsync(d_out, 0, (size_t)out_size * sizeof(float), stream);
  convert_w<<<dim3(512), dim3(256), 0, stream>>>(W, Wb);
  bilinear_kernel<<<dim3(2048), dim3(256), 0, stream>>>(elg, eth, Wb, out);
}

// Round 3
// 365.638 us; speedup vs baseline: 1.1032x; 1.0073x over previous
//
#include <hip/hip_runtime.h>
#include <hip/hip_bf16.h>

typedef __attribute__((ext_vector_type(8))) short short8;
typedef __attribute__((ext_vector_type(4))) float float4v;
typedef __attribute__((ext_vector_type(4))) unsigned int uint4v;

#define DDIM 1024
#define ETH_STRIDE 40   // fallback kernel only

__device__ __forceinline__ unsigned short f2bf(float f) {
  unsigned u = __builtin_bit_cast(unsigned, f);
  unsigned r = (u + 0x7fffu + ((u >> 16) & 1u)) >> 16;   // RNE
  return (unsigned short)r;
}
__device__ __forceinline__ unsigned pk2(float lo, float hi) {
  return (unsigned)f2bf(lo) | ((unsigned)f2bf(hi) << 16);
}
__device__ __forceinline__ void cvt8(const float* src, unsigned short* dst) {
  float4v a = *(const float4v*)(src);
  float4v b = *(const float4v*)(src + 4);
  uint4v pk;
  pk.x = pk2(a.x, a.y); pk.y = pk2(a.z, a.w);
  pk.z = pk2(b.x, b.y); pk.w = pk2(b.z, b.w);
  *(uint4v*)dst = pk;
}

// ---- prepass: W (1M elems) + eth (32M elems) fp32 -> bf16 in workspace ----
__global__ __launch_bounds__(256) void convert_all(const float* __restrict__ W,
                                                   const float* __restrict__ eth,
                                                   unsigned short* __restrict__ Wb,
                                                   unsigned short* __restrict__ ethB) {
  int b = blockIdx.x;
  if (b < 512) {
    size_t i = ((size_t)b * 256 + threadIdx.x) * 8;
    cvt8(W + i, Wb + i);
  } else {
    size_t i = ((size_t)(b - 512) * 256 + threadIdx.x) * 8;
    cvt8(eth + i, ethB + i);
  }
}
__global__ __launch_bounds__(256) void convert_w(const float* __restrict__ W,
                                                 unsigned short* __restrict__ Wb) {
  size_t i = ((size_t)blockIdx.x * 256 + threadIdx.x) * 8;
  cvt8(W + i, Wb + i);
}

// ---- main kernel (bf16-eth path): d-split, double-buffered, 1 barrier/iter ----
// grid 2048 = 512 m-groups x 4 d-tiles; block 256 (4 waves), wave tile 64x64.
// All staging via global_load_lds width-16; DMAs for chunk k+1 issued at top of
// iter k, drained at the barrier ending iter k (full-iteration latency window).
__global__ __launch_bounds__(256, 3) void bilinear_bf16(const float* __restrict__ elg,
                                                        const unsigned short* __restrict__ ethB,
                                                        const unsigned short* __restrict__ Wb,
                                                        float* __restrict__ out) {
  __shared__ unsigned short Wbuf[2][256 * 32];  // 32 KB, XOR-swizzled 16B units
  __shared__ unsigned short ethL[2][64 * 32];   // 8 KB
  __shared__ float wsum[4][64];                 // 1 KB

  const int tid  = threadIdx.x;
  const int lane = tid & 63;
  const int w    = tid >> 6;
  const int quad = lane >> 4;
  const int l15  = lane & 15;
  const int m0   = (blockIdx.x >> 2) * 64;
  const int d0   = (blockIdx.x & 3) * 256;
  const int wr = lane >> 2, wu = lane & 3;   // DMA row/unit role within a wave

  // stage K-chunk `ek` into buffer `buf` (5 DMA instrs per thread, no VGPR use)
  auto stage = [&](int ek, int buf) {
    const int e0 = ek * 32;
#pragma unroll
    for (int j = 0; j < 4; ++j) {            // W: 256 rows x 32 cols bf16 = 16 KB
      int r  = (w * 4 + j) * 16 + wr;
      int ug = wu ^ ((r >> 1) & 3);          // swizzle applied on the GLOBAL side
      const unsigned short* gp = Wb + (size_t)(d0 + r) * DDIM + e0 + ug * 8;
      unsigned short* lp = &Wbuf[buf][(w * 4 + j) * 512 + lane * 8];
      __builtin_amdgcn_global_load_lds(
          (const __attribute__((address_space(1))) unsigned int*)gp,
          (__attribute__((address_space(3))) unsigned int*)lp, 16, 0, 0);
    }
    {                                        // eth: 64 rows x 32 cols bf16 = 4 KB
      int er = w * 16 + wr;
      const unsigned short* gp = ethB + (size_t)(m0 + er) * DDIM + e0 + wu * 8;
      unsigned short* lp = &ethL[buf][w * 512 + lane * 8];
      __builtin_amdgcn_global_load_lds(
          (const __attribute__((address_space(1))) unsigned int*)gp,
          (__attribute__((address_space(3))) unsigned int*)lp, 16, 0, 0);
    }
  };

  float4v acc[4][4];
#pragma unroll
  for (int ct = 0; ct < 4; ++ct)
#pragma unroll
    for (int rt = 0; rt < 4; ++rt)
      acc[ct][rt] = (float4v){0.f, 0.f, 0.f, 0.f};

  stage(0, 0);
  __syncthreads();                           // chunk 0 visible

  for (int ek = 0; ek < 32; ++ek) {
    const int cur = ek & 1;
    if (ek < 31) stage(ek + 1, cur ^ 1);     // in flight across this whole iter

    short8 aF[4], bF[4];
#pragma unroll
    for (int rt = 0; rt < 4; ++rt)           // A[m=l15][k=quad*8+j], row-major 32
      aF[rt] = *(const short8*)&ethL[cur][(rt * 16 + l15) * 32 + quad * 8];
#pragma unroll
    for (int ct = 0; ct < 4; ++ct) {         // B row d, swizzled physical unit
      int dl = w * 64 + ct * 16 + l15;
      int pu = quad ^ ((dl >> 1) & 3);
      bF[ct] = *(const short8*)&Wbuf[cur][dl * 32 + pu * 8];
    }
#pragma unroll
    for (int ct = 0; ct < 4; ++ct)
#pragma unroll
      for (int rt = 0; rt < 4; ++rt)
        acc[ct][rt] = __builtin_amdgcn_mfma_f32_16x16x32_bf16(aF[rt], bF[ct], acc[ct][rt], 0, 0, 0);

    __syncthreads();                         // drains next-chunk DMAs; frees cur
  }

  // fused epilogue: p[m] = sum_col elg[m][col] * u[m][col] over this d-tile
  float p[16];
#pragma unroll
  for (int j = 0; j < 16; ++j) p[j] = 0.f;
#pragma unroll
  for (int ct = 0; ct < 4; ++ct) {
    int col = d0 + w * 64 + ct * 16 + l15;
#pragma unroll
    for (int rt = 0; rt < 4; ++rt) {
      const float* ep = elg + (size_t)(m0 + rt * 16 + quad * 4) * DDIM + col;
#pragma unroll
      for (int i = 0; i < 4; ++i)
        p[rt * 4 + i] += acc[ct][rt][i] * ep[(size_t)i * DDIM];
    }
  }
#pragma unroll
  for (int off = 1; off < 16; off <<= 1)
#pragma unroll
    for (int j = 0; j < 16; ++j)
      p[j] += __shfl_xor(p[j], off);
  if (l15 == 0) {
#pragma unroll
    for (int rt = 0; rt < 4; ++rt)
#pragma unroll
      for (int i = 0; i < 4; ++i)
        wsum[w][rt * 16 + quad * 4 + i] = p[rt * 4 + i];
  }
  __syncthreads();
  if (tid < 64) {
    float s = wsum[0][tid] + wsum[1][tid] + wsum[2][tid] + wsum[3][tid];
    atomicAdd(&out[m0 + tid], s);
  }
}

// ---- fallback (ws too small for eth_bf16): round-2 proven kernel ----
__global__ __launch_bounds__(256, 3) void bilinear_fp32eth(const float* __restrict__ elg,
                                                           const float* __restrict__ eth,
                                                           const unsigned short* __restrict__ Wb,
                                                           float* __restrict__ out) {
  __shared__ unsigned short ethL[64 * ETH_STRIDE];
  __shared__ unsigned short Wbuf[256 * 32];
  __shared__ float wsum[4][64];
  const int tid  = threadIdx.x;
  const int lane = tid & 63;
  const int w    = tid >> 6;
  const int quad = lane >> 4;
  const int l15  = lane & 15;
  const int m0   = (blockIdx.x >> 2) * 64;
  const int d0   = (blockIdx.x & 3) * 256;
  const int erow = tid >> 2, eunit = tid & 3;
  const float* esrc = eth + (size_t)(m0 + erow) * DDIM + eunit * 8;
  const int wr = lane >> 2, wu = lane & 3;
  float4v er0 = *(const float4v*)(esrc);
  float4v er1 = *(const float4v*)(esrc + 4);
  float4v acc[4][4];
#pragma unroll
  for (int ct = 0; ct < 4; ++ct)
#pragma unroll
    for (int rt = 0; rt < 4; ++rt)
      acc[ct][rt] = (float4v){0.f, 0.f, 0.f, 0.f};
  for (int ek = 0; ek < 32; ++ek) {
    const int e0 = ek * 32;
    __syncthreads();
    {
      uint4v pk;
      pk.x = pk2(er0.x, er0.y); pk.y = pk2(er0.z, er0.w);
      pk.z = pk2(er1.x, er1.y); pk.w = pk2(er1.z, er1.w);
      *(uint4v*)&ethL[erow * ETH_STRIDE + eunit * 8] = pk;
    }
#pragma unroll
    for (int j = 0; j < 4; ++j) {
      int r  = (w * 4 + j) * 16 + wr;
      int ug = wu ^ ((r >> 1) & 3);
      const unsigned short* gp = Wb + (size_t)(d0 + r) * DDIM + e0 + ug * 8;
      unsigned short* lp = &Wbuf[(w * 4 + j) * 512 + lane * 8];
      __builtin_amdgcn_global_load_lds(
          (const __attribute__((address_space(1))) unsigned int*)gp,
          (__attribute__((address_space(3))) unsigned int*)lp, 16, 0, 0);
    }
    __syncthreads();
    short8 aF[4], bF[4];
#pragma unroll
    for (int rt = 0; rt < 4; ++rt)
      aF[rt] = *(const short8*)&ethL[(rt * 16 + l15) * ETH_STRIDE + quad * 8];
#pragma unroll
    for (int ct = 0; ct < 4; ++ct) {
      int dl = w * 64 + ct * 16 + l15;
      int pu = quad ^ ((dl >> 1) & 3);
      bF[ct] = *(const short8*)&Wbuf[dl * 32 + pu * 8];
    }
    if (ek < 31) {
      const float* s = esrc + (e0 + 32);
      er0 = *(const float4v*)(s);
      er1 = *(const float4v*)(s + 4);
    }
#pragma unroll
    for (int ct = 0; ct < 4; ++ct)
#pragma unroll
      for (int rt = 0; rt < 4; ++rt)
        acc[ct][rt] = __builtin_amdgcn_mfma_f32_16x16x32_bf16(aF[rt], bF[ct], acc[ct][rt], 0, 0, 0);
  }
  float p[16];
#pragma unroll
  for (int j = 0; j < 16; ++j) p[j] = 0.f;
#pragma unroll
  for (int ct = 0; ct < 4; ++ct) {
    int col = d0 + w * 64 + ct * 16 + l15;
#pragma unroll
    for (int rt = 0; rt < 4; ++rt) {
      const float* ep = elg + (size_t)(m0 + rt * 16 + quad * 4) * DDIM + col;
#pragma unroll
      for (int i = 0; i < 4; ++i)
        p[rt * 4 + i] += acc[ct][rt][i] * ep[(size_t)i * DDIM];
    }
  }
#pragma unroll
  for (int off = 1; off < 16; off <<= 1)
#pragma unroll
    for (int j = 0; j < 16; ++j)
      p[j] += __shfl_xor(p[j], off);
  if (l15 == 0) {
#pragma unroll
    for (int rt = 0; rt < 4; ++rt)
#pragma unroll
      for (int i = 0; i < 4; ++i)
        wsum[w][rt * 16 + quad * 4 + i] = p[rt * 4 + i];
  }
  __syncthreads();
  if (tid < 64) {
    float s = wsum[0][tid] + wsum[1][tid] + wsum[2][tid] + wsum[3][tid];
    atomicAdd(&out[m0 + tid], s);
  }
}

extern "C" void kernel_launch(void* const* d_in, const int* in_sizes, int n_in,
                              void* d_out, int out_size, void* d_ws, size_t ws_size,
                              hipStream_t stream) {
  (void)in_sizes; (void)n_in;
  const float* elg = (const float*)d_in[0];
  const float* eth = (const float*)d_in[1];
  const float* W   = (const float*)d_in[2];
  float* out = (float*)d_out;
  unsigned short* Wb   = (unsigned short*)d_ws;                      // 2 MB
  unsigned short* ethB = (unsigned short*)((char*)d_ws + (2 << 20)); // 64 MB

  const size_t need = (2ull << 20) + (64ull << 20);
  hipMemsetAsync(d_out, 0, (size_t)out_size * sizeof(float), stream);
  if (ws_size >= need) {
    convert_all<<<dim3(512 + 16384), dim3(256), 0, stream>>>(W, eth, Wb, ethB);
    bilinear_bf16<<<dim3(2048), dim3(256), 0, stream>>>(elg, ethB, Wb, out);
  } else {
    convert_w<<<dim3(512), dim3(256), 0, stream>>>(W, Wb);
    bilinear_fp32eth<<<dim3(2048), dim3(256), 0, stream>>>(elg, eth, Wb, out);
  }
}

// Round 4
// 354.812 us; speedup vs baseline: 1.1369x; 1.0305x over previous
//
#include <hip/hip_runtime.h>
#include <hip/hip_bf16.h>

typedef __attribute__((ext_vector_type(8))) short short8;
typedef __attribute__((ext_vector_type(4))) float float4v;
typedef __attribute__((ext_vector_type(4))) unsigned int uint4v;

#define DDIM 1024

__device__ __forceinline__ unsigned short f2bf(float f) {
  unsigned u = __builtin_bit_cast(unsigned, f);
  unsigned r = (u + 0x7fffu + ((u >> 16) & 1u)) >> 16;   // RNE
  return (unsigned short)r;
}
__device__ __forceinline__ unsigned pk2(float lo, float hi) {
  return (unsigned)f2bf(lo) | ((unsigned)f2bf(hi) << 16);
}
__device__ __forceinline__ void cvt8(const float* src, unsigned short* dst) {
  float4v a = *(const float4v*)(src);
  float4v b = *(const float4v*)(src + 4);
  uint4v pk;
  pk.x = pk2(a.x, a.y); pk.y = pk2(a.z, a.w);
  pk.z = pk2(b.x, b.y); pk.w = pk2(b.z, b.w);
  *(uint4v*)dst = pk;
}

// ---- prepass: W (1M) + eth (32M) fp32 -> bf16 in workspace ----
__global__ __launch_bounds__(256) void convert_all(const float* __restrict__ W,
                                                   const float* __restrict__ eth,
                                                   unsigned short* __restrict__ Wb,
                                                   unsigned short* __restrict__ ethB) {
  int b = blockIdx.x;
  if (b < 512) {
    size_t i = ((size_t)b * 256 + threadIdx.x) * 8;
    cvt8(W + i, Wb + i);
  } else {
    size_t i = ((size_t)(b - 512) * 256 + threadIdx.x) * 8;
    cvt8(eth + i, ethB + i);
  }
}
__global__ __launch_bounds__(256) void convert_w(const float* __restrict__ W,
                                                 unsigned short* __restrict__ Wb) {
  size_t i = ((size_t)blockIdx.x * 256 + threadIdx.x) * 8;
  cvt8(W + i, Wb + i);
}

// ---- main: 128 rows x 128 d-cols per block, K=1024, dbuf, 1 barrier/iter ----
// grid 2048 = 256 m-groups x 8 d-tiles; d-tile = bid&7 pins each XCD to one
// 256 KB W slice (L2-resident). LDS 33 KB -> 4 blocks/CU (16 waves).
// Both A(eth) and B(W) staged via global_load_lds width-16, XOR unit swizzle.
__global__ __launch_bounds__(256, 4) void bilinear_bf16(const float* __restrict__ elg,
                                                        const unsigned short* __restrict__ ethB,
                                                        const unsigned short* __restrict__ Wb,
                                                        float* __restrict__ out) {
  __shared__ unsigned short Wbuf[2][128 * 32];  // 16 KB
  __shared__ unsigned short ethL[2][128 * 32];  // 16 KB
  __shared__ float wsum[4][64];                 // 1 KB

  const int tid  = threadIdx.x;
  const int lane = tid & 63;
  const int w    = tid >> 6;
  const int quad = lane >> 4;
  const int l15  = lane & 15;
  const int rowhalf = w >> 1;       // wave's 64-row half
  const int colhalf = w & 1;        // wave's 64-col half
  const int m0   = (blockIdx.x >> 3) * 128;
  const int d0   = (blockIdx.x & 7) * 128;
  const int wr = lane >> 2, wu = lane & 3;   // DMA row/unit role

  // stage K-chunk ek into buffer buf: 4 DMA instrs/thread, 16 KB total
  auto stage = [&](int ek, int buf) {
    const int e0 = ek * 32;
#pragma unroll
    for (int j = 0; j < 2; ++j) {
      const int R0 = w * 16 + j * 64;        // 16-row slab per wave-instr
      const int r  = R0 + wr;
      const int ug = wu ^ ((r >> 1) & 3);    // swizzle on the GLOBAL side
      const unsigned short* gw = Wb   + (size_t)(d0 + r) * DDIM + e0 + ug * 8;
      const unsigned short* ge = ethB + (size_t)(m0 + r) * DDIM + e0 + ug * 8;
      unsigned short* lw = &Wbuf[buf][R0 * 32 + lane * 8];
      unsigned short* le = &ethL[buf][R0 * 32 + lane * 8];
      __builtin_amdgcn_global_load_lds(
          (const __attribute__((address_space(1))) unsigned int*)gw,
          (__attribute__((address_space(3))) unsigned int*)lw, 16, 0, 0);
      __builtin_amdgcn_global_load_lds(
          (const __attribute__((address_space(1))) unsigned int*)ge,
          (__attribute__((address_space(3))) unsigned int*)le, 16, 0, 0);
    }
  };

  float4v acc[4][4];
#pragma unroll
  for (int ct = 0; ct < 4; ++ct)
#pragma unroll
    for (int rt = 0; rt < 4; ++rt)
      acc[ct][rt] = (float4v){0.f, 0.f, 0.f, 0.f};

  stage(0, 0);
  __syncthreads();

  for (int ek = 0; ek < 32; ++ek) {
    const int cur = ek & 1;
    if (ek < 31) stage(ek + 1, cur ^ 1);     // in flight across this whole iter

    short8 aF[4], bF[4];
#pragma unroll
    for (int rt = 0; rt < 4; ++rt) {         // A[m=l15][k=quad*8+j]
      int r  = rowhalf * 64 + rt * 16 + l15;
      int pu = quad ^ ((r >> 1) & 3);
      aF[rt] = *(const short8*)&ethL[cur][r * 32 + pu * 8];
    }
#pragma unroll
    for (int ct = 0; ct < 4; ++ct) {         // B[k][n=l15] = W row d
      int r  = colhalf * 64 + ct * 16 + l15;
      int pu = quad ^ ((r >> 1) & 3);
      bF[ct] = *(const short8*)&Wbuf[cur][r * 32 + pu * 8];
    }
#pragma unroll
    for (int ct = 0; ct < 4; ++ct)
#pragma unroll
      for (int rt = 0; rt < 4; ++rt)
        acc[ct][rt] = __builtin_amdgcn_mfma_f32_16x16x32_bf16(aF[rt], bF[ct], acc[ct][rt], 0, 0, 0);

    __syncthreads();                         // drains next-chunk DMAs; frees cur
  }

  // fused epilogue: p[m] = sum_col elg[m][col] * u[m][col] over this d-tile
  float p[16];
#pragma unroll
  for (int j = 0; j < 16; ++j) p[j] = 0.f;
#pragma unroll
  for (int ct = 0; ct < 4; ++ct) {
    int col = d0 + colhalf * 64 + ct * 16 + l15;
#pragma unroll
    for (int rt = 0; rt < 4; ++rt) {
      const float* ep = elg + (size_t)(m0 + rowhalf * 64 + rt * 16 + quad * 4) * DDIM + col;
#pragma unroll
      for (int i = 0; i < 4; ++i)
        p[rt * 4 + i] += acc[ct][rt][i] * ep[(size_t)i * DDIM];
    }
  }
#pragma unroll
  for (int off = 1; off < 16; off <<= 1)     // sum the 16 col-lanes per row
#pragma unroll
    for (int j = 0; j < 16; ++j)
      p[j] += __shfl_xor(p[j], off);
  if (l15 == 0) {
#pragma unroll
    for (int rt = 0; rt < 4; ++rt)
#pragma unroll
      for (int i = 0; i < 4; ++i)
        wsum[w][rt * 16 + quad * 4 + i] = p[rt * 4 + i];   // local row in half
  }
  __syncthreads();
  if (tid < 128) {
    int local = tid & 63, half = tid >> 6;
    float s = wsum[half * 2][local] + wsum[half * 2 + 1][local];
    atomicAdd(&out[m0 + tid], s);            // 8 d-tile blocks per output
  }
}

// ---- fallback (ws too small for eth_bf16): round-2 proven kernel ----
#define ETH_STRIDE 40
__global__ __launch_bounds__(256, 3) void bilinear_fp32eth(const float* __restrict__ elg,
                                                           const float* __restrict__ eth,
                                                           const unsigned short* __restrict__ Wb,
                                                           float* __restrict__ out) {
  __shared__ unsigned short ethL[64 * ETH_STRIDE];
  __shared__ unsigned short Wbuf[256 * 32];
  __shared__ float wsum[4][64];
  const int tid  = threadIdx.x;
  const int lane = tid & 63;
  const int w    = tid >> 6;
  const int quad = lane >> 4;
  const int l15  = lane & 15;
  const int m0   = (blockIdx.x >> 2) * 64;
  const int d0   = (blockIdx.x & 3) * 256;
  const int erow = tid >> 2, eunit = tid & 3;
  const float* esrc = eth + (size_t)(m0 + erow) * DDIM + eunit * 8;
  const int wr = lane >> 2, wu = lane & 3;
  float4v er0 = *(const float4v*)(esrc);
  float4v er1 = *(const float4v*)(esrc + 4);
  float4v acc[4][4];
#pragma unroll
  for (int ct = 0; ct < 4; ++ct)
#pragma unroll
    for (int rt = 0; rt < 4; ++rt)
      acc[ct][rt] = (float4v){0.f, 0.f, 0.f, 0.f};
  for (int ek = 0; ek < 32; ++ek) {
    const int e0 = ek * 32;
    __syncthreads();
    {
      uint4v pk;
      pk.x = pk2(er0.x, er0.y); pk.y = pk2(er0.z, er0.w);
      pk.z = pk2(er1.x, er1.y); pk.w = pk2(er1.z, er1.w);
      *(uint4v*)&ethL[erow * ETH_STRIDE + eunit * 8] = pk;
    }
#pragma unroll
    for (int j = 0; j < 4; ++j) {
      int r  = (w * 4 + j) * 16 + wr;
      int ug = wu ^ ((r >> 1) & 3);
      const unsigned short* gp = Wb + (size_t)(d0 + r) * DDIM + e0 + ug * 8;
      unsigned short* lp = &Wbuf[(w * 4 + j) * 512 + lane * 8];
      __builtin_amdgcn_global_load_lds(
          (const __attribute__((address_space(1))) unsigned int*)gp,
          (__attribute__((address_space(3))) unsigned int*)lp, 16, 0, 0);
    }
    __syncthreads();
    short8 aF[4], bF[4];
#pragma unroll
    for (int rt = 0; rt < 4; ++rt)
      aF[rt] = *(const short8*)&ethL[(rt * 16 + l15) * ETH_STRIDE + quad * 8];
#pragma unroll
    for (int ct = 0; ct < 4; ++ct) {
      int dl = w * 64 + ct * 16 + l15;
      int pu = quad ^ ((dl >> 1) & 3);
      bF[ct] = *(const short8*)&Wbuf[dl * 32 + pu * 8];
    }
    if (ek < 31) {
      const float* s = esrc + (e0 + 32);
      er0 = *(const float4v*)(s);
      er1 = *(const float4v*)(s + 4);
    }
#pragma unroll
    for (int ct = 0; ct < 4; ++ct)
#pragma unroll
      for (int rt = 0; rt < 4; ++rt)
        acc[ct][rt] = __builtin_amdgcn_mfma_f32_16x16x32_bf16(aF[rt], bF[ct], acc[ct][rt], 0, 0, 0);
  }
  float p[16];
#pragma unroll
  for (int j = 0; j < 16; ++j) p[j] = 0.f;
#pragma unroll
  for (int ct = 0; ct < 4; ++ct) {
    int col = d0 + w * 64 + ct * 16 + l15;
#pragma unroll
    for (int rt = 0; rt < 4; ++rt) {
      const float* ep = elg + (size_t)(m0 + rt * 16 + quad * 4) * DDIM + col;
#pragma unroll
      for (int i = 0; i < 4; ++i)
        p[rt * 4 + i] += acc[ct][rt][i] * ep[(size_t)i * DDIM];
    }
  }
#pragma unroll
  for (int off = 1; off < 16; off <<= 1)
#pragma unroll
    for (int j = 0; j < 16; ++j)
      p[j] += __shfl_xor(p[j], off);
  if (l15 == 0) {
#pragma unroll
    for (int rt = 0; rt < 4; ++rt)
#pragma unroll
      for (int i = 0; i < 4; ++i)
        wsum[w][rt * 16 + quad * 4 + i] = p[rt * 4 + i];
  }
  __syncthreads();
  if (tid < 64) {
    float s = wsum[0][tid] + wsum[1][tid] + wsum[2][tid] + wsum[3][tid];
    atomicAdd(&out[m0 + tid], s);
  }
}

extern "C" void kernel_launch(void* const* d_in, const int* in_sizes, int n_in,
                              void* d_out, int out_size, void* d_ws, size_t ws_size,
                              hipStream_t stream) {
  (void)in_sizes; (void)n_in;
  const float* elg = (const float*)d_in[0];
  const float* eth = (const float*)d_in[1];
  const float* W   = (const float*)d_in[2];
  float* out = (float*)d_out;
  unsigned short* Wb   = (unsigned short*)d_ws;                      // 2 MB
  unsigned short* ethB = (unsigned short*)((char*)d_ws + (2 << 20)); // 64 MB

  const size_t need = (2ull << 20) + (64ull << 20);
  hipMemsetAsync(d_out, 0, (size_t)out_size * sizeof(float), stream);
  if (ws_size >= need) {
    convert_all<<<dim3(512 + 16384), dim3(256), 0, stream>>>(W, eth, Wb, ethB);
    bilinear_bf16<<<dim3(2048), dim3(256), 0, stream>>>(elg, ethB, Wb, out);
  } else {
    convert_w<<<dim3(512), dim3(256), 0, stream>>>(W, Wb);
    bilinear_fp32eth<<<dim3(2048), dim3(256), 0, stream>>>(elg, eth, Wb, out);
  }
}